// Round 19
// baseline (184.726 us; speedup 1.0000x reference)
//
#include <hip/hip_runtime.h>

#define NN 50000
#define EE 800000
#define NB ((NN + 1023) / 1024)    // 49 scan blocks
#define DEGB ((EE + 255) / 256)    // 3125 edge-parallel blocks (256-thr)
#define GEMMB ((NN + 63) / 64)     // 782 gemm tile blocks (BN=256: one block-column)
#define FILLB ((EE + 511) / 512)   // 1563 fill blocks (512-thr)

typedef _Float16 half8v __attribute__((ext_vector_type(8)));
typedef float f32x4 __attribute__((ext_vector_type(4)));

// async global->LDS 16B (LDS dest = wave-uniform base + lane*16, linear order)
__device__ __forceinline__ void gload16(const void* g, void* l) {
    __builtin_amdgcn_global_load_lds(
        (const __attribute__((address_space(1))) unsigned int*)g,
        (__attribute__((address_space(3))) unsigned int*)l, 16, 0, 0);
}

// ---- deg_prep: deg+epos atomics (0..DEGB-1) | W1 transpose (16) | projections (1) ----
__global__ __launch_bounds__(256) void deg_prep(const int* __restrict__ dst,
                                                int* __restrict__ deg,
                                                int* __restrict__ epos,
                                                const float* __restrict__ W1,
                                                const float* __restrict__ W2,
                                                const float* __restrict__ fW1,
                                                const float* __restrict__ emb0,
                                                const float* __restrict__ emb1,
                                                _Float16* __restrict__ BT,
                                                float* __restrict__ Wft,
                                                float2* __restrict__ t0,
                                                float2* __restrict__ t1) {
    __shared__ float T[64][65];
    int b = blockIdx.x;
    int t = threadIdx.x;
    if (b < DEGB) {
        int e = b * 256 + t;
        if (e < EE) epos[e] = atomicAdd(&deg[dst[e]], 1);
    } else if (b < DEGB + 16) {
        int bb = b - DEGB;
        int k0 = (bb >> 2) * 64, n0 = (bb & 3) * 64;
#pragma unroll
        for (int i = 0; i < 16; ++i) {
            int r = i * 4 + (t >> 6), c = t & 63;
            T[r][c] = W1[(size_t)(k0 + r) * 256 + n0 + c];
        }
        __syncthreads();
#pragma unroll
        for (int i = 0; i < 16; ++i) {
            int n = i * 4 + (t >> 6), k = t & 63;
            BT[(size_t)(n0 + n) * 256 + k0 + k] = (_Float16)T[k][n];
        }
    } else {
        int k = t;
        float s0 = 0.f, s1 = 0.f;
        for (int m = 0; m < 128; ++m) {
            float wv = W2[(size_t)k * 128 + m];
            s0 += wv * fW1[m * 2 + 0];
            s1 += wv * fW1[m * 2 + 1];
        }
        Wft[k] = s0;
        Wft[256 + k] = s1;
        if (k < 20) {
            float a0 = 0.f, a1 = 0.f, b0 = 0.f, b1v = 0.f;
            for (int u = 0; u < 32; ++u) {
                float e0 = emb0[k * 32 + u], e1 = emb1[k * 32 + u];
                a0 += e0 * fW1[(130 + u) * 2 + 0];
                a1 += e0 * fW1[(130 + u) * 2 + 1];
                b0 += e1 * fW1[(162 + u) * 2 + 0];
                b1v += e1 * fW1[(162 + u) * 2 + 1];
            }
            t0[k] = make_float2(a0, a1);
            t1[k] = make_float2(b0, b1v);
        }
    }
}

// ---------------- scan phase 1 ----------------
__global__ __launch_bounds__(1024) void scan_partial(const int* __restrict__ deg,
                                                     int* __restrict__ rowptr,
                                                     int* __restrict__ bsum) {
    __shared__ int wsum[16];
    int tid = threadIdx.x, lane = tid & 63, w = tid >> 6;
    int idx = blockIdx.x * 1024 + tid;
    int v = (idx < NN) ? deg[idx] : 0;
    int x = v;
#pragma unroll
    for (int off = 1; off < 64; off <<= 1) {
        int t = __shfl_up(x, off, 64);
        if (lane >= off) x += t;
    }
    if (lane == 63) wsum[w] = x;
    __syncthreads();
    if (w == 0) {
        int s = (lane < 16) ? wsum[lane] : 0;
#pragma unroll
        for (int off = 1; off < 16; off <<= 1) {
            int t = __shfl_up(s, off, 64);
            if (lane >= off) s += t;
        }
        if (lane < 16) wsum[lane] = s;
    }
    __syncthreads();
    int wpre = (w == 0) ? 0 : wsum[w - 1];
    if (idx < NN) rowptr[idx] = wpre + (x - v);
    if (tid == 0) bsum[blockIdx.x] = wsum[15];
}

// ---------------- scan phase 2 ----------------
__global__ __launch_bounds__(256) void scan_add_dinv(int* __restrict__ rowptr,
                                                     const int* __restrict__ bsum,
                                                     const int* __restrict__ deg,
                                                     float* __restrict__ dinv) {
    __shared__ int pre[NB + 1];
    int t = threadIdx.x;
    if (t < 64) {
        int v = (t < NB) ? bsum[t] : 0;
        int x = v;
#pragma unroll
        for (int o = 1; o < 64; o <<= 1) {
            int y = __shfl_up(x, o, 64);
            if (t >= o) x += y;
        }
        if (t < NB) pre[t] = x - v;
        if (t == NB - 1) pre[NB] = x;
    }
    __syncthreads();
    int idx = blockIdx.x * 256 + t;
    if (idx < NN) {
        rowptr[idx] += pre[idx >> 10];
        dinv[idx] = rsqrtf((float)deg[idx] + 1.0f);
    }
    if (blockIdx.x == 0 && t == 0) rowptr[NN] = pre[NB];
}

// ---- fused: MFMA fp16 GEMM (A via gload_lds dbuf; B DIRECT from L2, reg-prefetched)
//      + atomic-free CSR fill ----
__global__ __launch_bounds__(512) void gemm_fill(const float* __restrict__ A,
                                                 const _Float16* __restrict__ BT,
                                                 _Float16* __restrict__ C, int M,
                                                 const int* __restrict__ src,
                                                 const int* __restrict__ dst,
                                                 const int* __restrict__ rowptr,
                                                 const int* __restrict__ epos,
                                                 int* __restrict__ csr_src) {
    if (blockIdx.x >= GEMMB) {
        int e = (blockIdx.x - GEMMB) * 512 + threadIdx.x;
        if (e < EE) {
            int d = dst[e];
            csr_src[rowptr[d] + epos[e]] = src[e];
        }
        return;
    }
    __shared__ float Ahf[2][2048];          // 2 x 8 KB f32, chunk layout [q][r]; only A staged
    int tid = threadIdx.x;
    int bm = blockIdx.x * 64;
    int w = tid >> 6, l = tid & 63;
    int wr = w >> 2, wc = w & 3;            // 8 waves: 2 row-groups x 4 col-groups
    int lr = l & 15, lg = l >> 4;
    f32x4 acc[2][4] = {};

    int ar = tid & 63, aq = tid >> 6;
    int garow = bm + ar; if (garow >= M) garow = M - 1;
    const float* gA = A + (size_t)garow * 256 + aq * 4;
    // per-lane B base: row (wc*64 + nf*16 + lr), k-octet lg
    const _Float16* gB = BT + (size_t)(wc * 64 + lr) * 256 + lg * 8;

    half8v bcur[4], bnxt[4];
    auto loadB = [&](half8v* d4, int k0) {
#pragma unroll
        for (int nf = 0; nf < 4; ++nf)
            d4[nf] = *(const half8v*)(gB + (size_t)nf * 16 * 256 + k0);
    };

    gload16(gA, &Ahf[0][tid * 4]);          // stage A tile 0
    loadB(bcur, 0);                          // B frags for step 0 (L2)
    __syncthreads();                         // drains: A tile 0 resident
#pragma unroll
    for (int ks = 0; ks < 8; ++ks) {
        int cur = ks & 1;
        if (ks < 7) {
            gload16(gA + (ks + 1) * 32, &Ahf[cur ^ 1][tid * 4]);   // prefetch A
            loadB(bnxt, (ks + 1) * 32);                            // prefetch B (L2)
        }
        half8v a[2];
#pragma unroll
        for (int mf = 0; mf < 2; ++mf) {
            int r = wr * 32 + mf * 16 + lr;
            int q0 = 2 * lg;
            f32x4 va = *(const f32x4*)&Ahf[cur][(q0 * 64 + r) * 4];
            f32x4 vb = *(const f32x4*)&Ahf[cur][((q0 + 1) * 64 + r) * 4];
            half8v h;
            h[0] = (_Float16)va[0]; h[1] = (_Float16)va[1];
            h[2] = (_Float16)va[2]; h[3] = (_Float16)va[3];
            h[4] = (_Float16)vb[0]; h[5] = (_Float16)vb[1];
            h[6] = (_Float16)vb[2]; h[7] = (_Float16)vb[3];
            a[mf] = h;
        }
#pragma unroll
        for (int mf = 0; mf < 2; ++mf)
#pragma unroll
            for (int nf = 0; nf < 4; ++nf)
                acc[mf][nf] = __builtin_amdgcn_mfma_f32_16x16x32_f16(a[mf], bcur[nf], acc[mf][nf], 0, 0, 0);
#pragma unroll
        for (int nf = 0; nf < 4; ++nf) bcur[nf] = bnxt[nf];
        __syncthreads();                     // drain: next A tile resident; cur reads done
    }
    // epilogue: D row = (lane>>4)*4 + reg, col = lane&15
#pragma unroll
    for (int mf = 0; mf < 2; ++mf) {
#pragma unroll
        for (int reg = 0; reg < 4; ++reg) {
            int gr = bm + wr * 32 + mf * 16 + lg * 4 + reg;
            if (gr < M) {
#pragma unroll
                for (int nf = 0; nf < 4; ++nf)
                    C[(size_t)gr * 256 + wc * 64 + nf * 16 + lr] =
                        (_Float16)acc[mf][nf][reg];
            }
        }
    }
}

// ---------------- fused gather (fp16 rows, per-src dinv fma) + relu + 2-col projection -------
__global__ __launch_bounds__(256) void gather_project(const _Float16* __restrict__ hs,
                                                      const int* __restrict__ rowptr,
                                                      const int* __restrict__ csr_src,
                                                      const float* __restrict__ dinv,
                                                      const float* __restrict__ b1,
                                                      const float* __restrict__ Wft,
                                                      float2* __restrict__ q,
                                                      int base, int cnt) {
    int i = base + blockIdx.x * 4 + (threadIdx.x >> 6);
    int l = threadIdx.x & 63;
    int lf = l & 31, le = l >> 5;
    if (i >= base + cnt || i >= NN) return;
    int start = rowptr[i], end = rowptr[i + 1];
    float acc[8] = {};
    int j = start;
    for (; j + 7 < end; j += 8) {
        int s0 = csr_src[j + 0 + le];
        int s1 = csr_src[j + 2 + le];
        int s2 = csr_src[j + 4 + le];
        int s3 = csr_src[j + 6 + le];
        float d0 = dinv[s0], d1 = dinv[s1], d2 = dinv[s2], d3 = dinv[s3];
        half8v v0 = *(const half8v*)(hs + (size_t)s0 * 256 + lf * 8);
        half8v v1 = *(const half8v*)(hs + (size_t)s1 * 256 + lf * 8);
        half8v v2 = *(const half8v*)(hs + (size_t)s2 * 256 + lf * 8);
        half8v v3 = *(const half8v*)(hs + (size_t)s3 * 256 + lf * 8);
#pragma unroll
        for (int u = 0; u < 8; ++u)
            acc[u] += (d0 * (float)v0[u] + d1 * (float)v1[u]) +
                      (d2 * (float)v2[u] + d3 * (float)v3[u]);
    }
    for (; j + le < end; j += 2) {
        int s = csr_src[j + le];
        float ds = dinv[s];
        half8v v = *(const half8v*)(hs + (size_t)s * 256 + lf * 8);
#pragma unroll
        for (int u = 0; u < 8; ++u) acc[u] += ds * (float)v[u];
    }
#pragma unroll
    for (int u = 0; u < 8; ++u) acc[u] += __shfl_xor(acc[u], 32, 64);
    float di = dinv[i];
    half8v sv = *(const half8v*)(hs + (size_t)i * 256 + lf * 8);
    float q0 = 0.f, q1 = 0.f;
#pragma unroll
    for (int u = 0; u < 8; ++u) {
        float o = fmaxf((acc[u] + di * (float)sv[u]) * di + b1[lf * 8 + u], 0.f);
        q0 += o * Wft[lf * 8 + u];
        q1 += o * Wft[256 + lf * 8 + u];
    }
#pragma unroll
    for (int off = 16; off > 0; off >>= 1) {
        q0 += __shfl_xor(q0, off, 64);
        q1 += __shfl_xor(q1, off, 64);
    }
    if (l == 0) q[i] = make_float2(q0 * di, q1 * di);
}

// ---------------- gn[i] = (sum_j q[j] + q[i]) * dinv[i] ----------------
__global__ __launch_bounds__(256) void gather_gn(const float2* __restrict__ q,
                                                 const int* __restrict__ rowptr,
                                                 const int* __restrict__ csr_src,
                                                 const float* __restrict__ dinv,
                                                 float2* __restrict__ gn) {
    int i = blockIdx.x * blockDim.x + threadIdx.x;
    if (i >= NN) return;
    int start = rowptr[i], end = rowptr[i + 1];
    float a0 = 0.f, a1 = 0.f;
    for (int j = start; j < end; ++j) {
        float2 v = q[csr_src[j]];
        a0 += v.x;
        a1 += v.y;
    }
    float2 self = q[i];
    float di = dinv[i];
    gn[i] = make_float2((a0 + self.x) * di, (a1 + self.y) * di);
}

// ---------------- final edge kernel ----------------
__global__ __launch_bounds__(256) void edge_out(const float2* __restrict__ gn,
                                                const int* __restrict__ src,
                                                const int* __restrict__ dst,
                                                const int2* __restrict__ ecat,
                                                const float2* __restrict__ ev,
                                                const float* __restrict__ fW1,
                                                const float2* __restrict__ t0,
                                                const float2* __restrict__ t1,
                                                const float* __restrict__ fb1,
                                                const float* __restrict__ fW2,
                                                const float* __restrict__ fb2,
                                                float2* __restrict__ out) {
    int e = blockIdx.x * blockDim.x + threadIdx.x;
    if (e >= EE) return;
    int s = src[e], d = dst[e];
    float2 gs = gn[s], gd = gn[d];
    int2 c = ecat[e];
    float2 v = ev[e];
    float2 e0 = t0[c.x], e1 = t1[c.y];
    float z0 = gs.x - gd.x + v.x * fW1[128 * 2 + 0] + v.y * fW1[129 * 2 + 0] + e0.x + e1.x;
    float z1 = gs.y - gd.y + v.x * fW1[128 * 2 + 1] + v.y * fW1[129 * 2 + 1] + e0.y + e1.y;
    float y0 = fmaxf(z0 + fb1[0], 0.f);
    float y1 = fmaxf(z1 + fb1[1], 0.f);
    out[e] = make_float2(y0 * fW2[0] + y1 * fW2[2] + fb2[0],
                         y0 * fW2[1] + y1 * fW2[3] + fb2[1]);
}

extern "C" void kernel_launch(void* const* d_in, const int* in_sizes, int n_in,
                              void* d_out, int out_size, void* d_ws, size_t ws_size,
                              hipStream_t stream) {
    const float* x    = (const float*)d_in[0];
    const int*   eidx = (const int*)d_in[1];
    const int*   src  = eidx;
    const int*   dst  = eidx + EE;
    const int*   ecat = (const int*)d_in[2];
    const float* ev   = (const float*)d_in[3];
    const float* W1   = (const float*)d_in[4];
    const float* b1   = (const float*)d_in[5];
    const float* W2   = (const float*)d_in[6];
    // b2 (d_in[7]) cancels in gn[s]-gn[d]; unused.
    const float* emb0 = (const float*)d_in[8];
    const float* emb1 = (const float*)d_in[9];
    const float* fW1  = (const float*)d_in[10];
    const float* fb1  = (const float*)d_in[11];
    const float* fW2  = (const float*)d_in[12];
    const float* fb2  = (const float*)d_in[13];
    float* out = (float*)d_out;

    char* ws = (char*)d_ws;
    size_t off = 0;
    auto alloc = [&](size_t bytes) {
        void* p = ws + off;
        off = (off + bytes + 255) & ~(size_t)255;
        return p;
    };
    int*      deg     = (int*)alloc((size_t)NN * 4);
    float*    dinv    = (float*)alloc((size_t)NN * 4);
    int*      rowptr  = (int*)alloc((size_t)(NN + 1) * 4);
    int*      bsum    = (int*)alloc((size_t)NB * 4);
    int*      epos    = (int*)alloc((size_t)EE * 4);
    int*      csr_src = (int*)alloc((size_t)EE * 4);
    _Float16* W1T     = (_Float16*)alloc((size_t)256 * 256 * 2);
    _Float16* h1s     = (_Float16*)alloc((size_t)NN * 256 * 2);    // 25.6 MB fp16
    float2*   q       = (float2*)alloc((size_t)NN * 8);
    float2*   gn      = (float2*)alloc((size_t)NN * 8);
    float*    Wft     = (float*)alloc(512 * 4);
    float2*   t0      = (float2*)alloc(20 * 8);
    float2*   t1      = (float2*)alloc(20 * 8);

    hipMemsetAsync(deg, 0, (size_t)NN * 4, stream);

    // deg/epos atomics + W1 transpose + tiny projections (one dispatch)
    deg_prep<<<DEGB + 17, 256, 0, stream>>>(dst, deg, epos,
                                            W1, W2, fW1, emb0, emb1,
                                            W1T, Wft, t0, t1);

    // scan -> rowptr (+dinv)
    scan_partial<<<NB, 1024, 0, stream>>>(deg, rowptr, bsum);
    scan_add_dinv<<<(NN + 255) / 256, 256, 0, stream>>>(rowptr, bsum, deg, dinv);

    // GEMM (A-only LDS dbuf; B direct from L2) fused with atomic-free CSR fill
    gemm_fill<<<GEMMB + FILLB, 512, 0, stream>>>(x, W1T, h1s, NN,
                                                 src, dst, rowptr, epos, csr_src);

    // fused gather + relu + project -> q [N,2]  (two halves)
    {
        int half1 = NN / 2;
        int half2 = NN - half1;
        gather_project<<<(half1 + 3) / 4, 256, 0, stream>>>(
            h1s, rowptr, csr_src, dinv, b1, Wft, q, 0, half1);
        gather_project<<<(half2 + 3) / 4, 256, 0, stream>>>(
            h1s, rowptr, csr_src, dinv, b1, Wft, q, half1, half2);
    }
    // gn
    gather_gn<<<(NN + 255) / 256, 256, 0, stream>>>(q, rowptr, csr_src, dinv, gn);
    // edges
    edge_out<<<(EE + 255) / 256, 256, 0, stream>>>(
        gn, src, dst, (const int2*)ecat, (const float2*)ev,
        fW1, t0, t1, fb1, fW2, fb2, (float2*)out);
}

// Round 20
// 161.962 us; speedup vs baseline: 1.1406x; 1.1406x over previous
//
#include <hip/hip_runtime.h>

#define NN 50000
#define EE 800000
#define NB ((NN + 1023) / 1024)    // 49 scan blocks
#define DEGB ((EE + 255) / 256)    // 3125 edge-parallel blocks (256-thr)
#define GEMMB ((NN + 63) / 64)     // 782 gemm tile blocks (BN=256: one block-column)
#define FILLB ((EE + 511) / 512)   // 1563 fill blocks (512-thr)

typedef _Float16 half8v __attribute__((ext_vector_type(8)));
typedef float f32x4 __attribute__((ext_vector_type(4)));

// async global->LDS 16B (LDS dest = wave-uniform base + lane*16, linear order)
__device__ __forceinline__ void gload16(const void* g, void* l) {
    __builtin_amdgcn_global_load_lds(
        (const __attribute__((address_space(1))) unsigned int*)g,
        (__attribute__((address_space(3))) unsigned int*)l, 16, 0, 0);
}

// ---- deg_prep: deg+epos atomics (0..DEGB-1) | W1 transpose (16) | projections (1) ----
__global__ __launch_bounds__(256) void deg_prep(const int* __restrict__ dst,
                                                int* __restrict__ deg,
                                                int* __restrict__ epos,
                                                const float* __restrict__ W1,
                                                const float* __restrict__ W2,
                                                const float* __restrict__ fW1,
                                                const float* __restrict__ emb0,
                                                const float* __restrict__ emb1,
                                                _Float16* __restrict__ BT,
                                                float* __restrict__ Wft,
                                                float2* __restrict__ t0,
                                                float2* __restrict__ t1) {
    __shared__ float T[64][65];
    int b = blockIdx.x;
    int t = threadIdx.x;
    if (b < DEGB) {
        int e = b * 256 + t;
        if (e < EE) epos[e] = atomicAdd(&deg[dst[e]], 1);
    } else if (b < DEGB + 16) {
        int bb = b - DEGB;
        int k0 = (bb >> 2) * 64, n0 = (bb & 3) * 64;
#pragma unroll
        for (int i = 0; i < 16; ++i) {
            int r = i * 4 + (t >> 6), c = t & 63;
            T[r][c] = W1[(size_t)(k0 + r) * 256 + n0 + c];
        }
        __syncthreads();
#pragma unroll
        for (int i = 0; i < 16; ++i) {
            int n = i * 4 + (t >> 6), k = t & 63;
            BT[(size_t)(n0 + n) * 256 + k0 + k] = (_Float16)T[k][n];
        }
    } else {
        int k = t;
        float s0 = 0.f, s1 = 0.f;
        for (int m = 0; m < 128; ++m) {
            float wv = W2[(size_t)k * 128 + m];
            s0 += wv * fW1[m * 2 + 0];
            s1 += wv * fW1[m * 2 + 1];
        }
        Wft[k] = s0;
        Wft[256 + k] = s1;
        if (k < 20) {
            float a0 = 0.f, a1 = 0.f, b0 = 0.f, b1v = 0.f;
            for (int u = 0; u < 32; ++u) {
                float e0 = emb0[k * 32 + u], e1 = emb1[k * 32 + u];
                a0 += e0 * fW1[(130 + u) * 2 + 0];
                a1 += e0 * fW1[(130 + u) * 2 + 1];
                b0 += e1 * fW1[(162 + u) * 2 + 0];
                b1v += e1 * fW1[(162 + u) * 2 + 1];
            }
            t0[k] = make_float2(a0, a1);
            t1[k] = make_float2(b0, b1v);
        }
    }
}

// ---------------- scan phase 1 ----------------
__global__ __launch_bounds__(1024) void scan_partial(const int* __restrict__ deg,
                                                     int* __restrict__ rowptr,
                                                     int* __restrict__ bsum) {
    __shared__ int wsum[16];
    int tid = threadIdx.x, lane = tid & 63, w = tid >> 6;
    int idx = blockIdx.x * 1024 + tid;
    int v = (idx < NN) ? deg[idx] : 0;
    int x = v;
#pragma unroll
    for (int off = 1; off < 64; off <<= 1) {
        int t = __shfl_up(x, off, 64);
        if (lane >= off) x += t;
    }
    if (lane == 63) wsum[w] = x;
    __syncthreads();
    if (w == 0) {
        int s = (lane < 16) ? wsum[lane] : 0;
#pragma unroll
        for (int off = 1; off < 16; off <<= 1) {
            int t = __shfl_up(s, off, 64);
            if (lane >= off) s += t;
        }
        if (lane < 16) wsum[lane] = s;
    }
    __syncthreads();
    int wpre = (w == 0) ? 0 : wsum[w - 1];
    if (idx < NN) rowptr[idx] = wpre + (x - v);
    if (tid == 0) bsum[blockIdx.x] = wsum[15];
}

// ---------------- scan phase 2 ----------------
__global__ __launch_bounds__(256) void scan_add_dinv(int* __restrict__ rowptr,
                                                     const int* __restrict__ bsum,
                                                     const int* __restrict__ deg,
                                                     float* __restrict__ dinv) {
    __shared__ int pre[NB + 1];
    int t = threadIdx.x;
    if (t < 64) {
        int v = (t < NB) ? bsum[t] : 0;
        int x = v;
#pragma unroll
        for (int o = 1; o < 64; o <<= 1) {
            int y = __shfl_up(x, o, 64);
            if (t >= o) x += y;
        }
        if (t < NB) pre[t] = x - v;
        if (t == NB - 1) pre[NB] = x;
    }
    __syncthreads();
    int idx = blockIdx.x * 256 + t;
    if (idx < NN) {
        rowptr[idx] += pre[idx >> 10];
        dinv[idx] = rsqrtf((float)deg[idx] + 1.0f);
    }
    if (blockIdx.x == 0 && t == 0) rowptr[NN] = pre[NB];
}

// ---- fused: atomic-free CSR fill (blocks 0..FILLB-1, launch first) +
//      MFMA fp16 GEMM (f32 A + fp16 B via gload_lds, counted-vmcnt dbuf, setprio) ----
__global__ __launch_bounds__(512) void gemm_fill(const float* __restrict__ A,
                                                 const _Float16* __restrict__ BT,
                                                 _Float16* __restrict__ C, int M,
                                                 const int* __restrict__ src,
                                                 const int* __restrict__ dst,
                                                 const int* __restrict__ rowptr,
                                                 const int* __restrict__ epos,
                                                 int* __restrict__ csr_src) {
    if (blockIdx.x < FILLB) {
        int e = blockIdx.x * 512 + threadIdx.x;
        if (e < EE) {
            int d = dst[e];
            csr_src[rowptr[d] + epos[e]] = src[e];
        }
        return;
    }
    __shared__ float    Ahf[2][2048];       // 2 x 8 KB f32, chunk layout [q][r]
    __shared__ _Float16 Bh[2][256 * 32];    // 2 x 16 KB fp16, [n][k]
    int tid = threadIdx.x;
    int bm = (blockIdx.x - FILLB) * 64;
    int w = tid >> 6, l = tid & 63;
    int wr = w >> 2, wc = w & 3;            // 8 waves: 2 row-groups x 4 col-groups
    int lr = l & 15, lg = l >> 4;
    f32x4 acc[2][4] = {};

    int ar = tid & 63, aq = tid >> 6;
    int garow = bm + ar; if (garow >= M) garow = M - 1;
    const float* gA = A + (size_t)garow * 256 + aq * 4;
    const _Float16* gB0 = BT + (size_t)(tid >> 2) * 256 + (tid & 3) * 8;
    const _Float16* gB1 = BT + (size_t)((tid >> 2) + 128) * 256 + (tid & 3) * 8;

    auto stage = [&](int buf, int k0) {
        gload16(gA + k0, &Ahf[buf][tid * 4]);
        gload16(gB0 + k0, &Bh[buf][tid * 8]);
        gload16(gB1 + k0, &Bh[buf][(tid + 512) * 8]);
    };

    stage(0, 0);                             // 3 loads in flight for buf0
#pragma unroll
    for (int ks = 0; ks < 8; ++ks) {
        int cur = ks & 1;
        if (ks < 7) {
            stage(cur ^ 1, (ks + 1) * 32);   // issue next tile (3 more in flight)
            asm volatile("s_waitcnt vmcnt(3)" ::: "memory");  // cur's 3 loads done
        } else {
            asm volatile("s_waitcnt vmcnt(0)" ::: "memory");  // last tile: drain
        }
        __builtin_amdgcn_s_barrier();        // raw: no compiler vmcnt(0) drain
        __builtin_amdgcn_sched_barrier(0);   // fence: no hoisting reads above
        half8v a[2], b[4];
#pragma unroll
        for (int mf = 0; mf < 2; ++mf) {
            int r = wr * 32 + mf * 16 + lr;
            int q0 = 2 * lg;
            f32x4 va = *(const f32x4*)&Ahf[cur][(q0 * 64 + r) * 4];
            f32x4 vb = *(const f32x4*)&Ahf[cur][((q0 + 1) * 64 + r) * 4];
            half8v h;
            h[0] = (_Float16)va[0]; h[1] = (_Float16)va[1];
            h[2] = (_Float16)va[2]; h[3] = (_Float16)va[3];
            h[4] = (_Float16)vb[0]; h[5] = (_Float16)vb[1];
            h[6] = (_Float16)vb[2]; h[7] = (_Float16)vb[3];
            a[mf] = h;
        }
#pragma unroll
        for (int nf = 0; nf < 4; ++nf)
            b[nf] = *(const half8v*)&Bh[cur][(wc * 64 + nf * 16 + lr) * 32 + lg * 8];
        __builtin_amdgcn_s_setprio(1);
#pragma unroll
        for (int mf = 0; mf < 2; ++mf)
#pragma unroll
            for (int nf = 0; nf < 4; ++nf)
                acc[mf][nf] = __builtin_amdgcn_mfma_f32_16x16x32_f16(a[mf], b[nf], acc[mf][nf], 0, 0, 0);
        __builtin_amdgcn_s_setprio(0);
        if (ks < 7) {
            __builtin_amdgcn_sched_barrier(0);
            __builtin_amdgcn_s_barrier();    // all waves done reading cur before
        }                                    // next step's stage overwrites it
    }
    // epilogue: D row = (lane>>4)*4 + reg, col = lane&15
#pragma unroll
    for (int mf = 0; mf < 2; ++mf) {
#pragma unroll
        for (int reg = 0; reg < 4; ++reg) {
            int gr = bm + wr * 32 + mf * 16 + lg * 4 + reg;
            if (gr < M) {
#pragma unroll
                for (int nf = 0; nf < 4; ++nf)
                    C[(size_t)gr * 256 + wc * 64 + nf * 16 + lr] =
                        (_Float16)acc[mf][nf][reg];
            }
        }
    }
}

// ---------------- fused gather (fp16 rows, per-src dinv fma) + relu + 2-col projection -------
__global__ __launch_bounds__(256) void gather_project(const _Float16* __restrict__ hs,
                                                      const int* __restrict__ rowptr,
                                                      const int* __restrict__ csr_src,
                                                      const float* __restrict__ dinv,
                                                      const float* __restrict__ b1,
                                                      const float* __restrict__ Wft,
                                                      float2* __restrict__ q) {
    int i = blockIdx.x * 4 + (threadIdx.x >> 6);
    int l = threadIdx.x & 63;
    int lf = l & 31, le = l >> 5;
    if (i >= NN) return;
    int start = rowptr[i], end = rowptr[i + 1];
    float acc[8] = {};
    int j = start;
    for (; j + 7 < end; j += 8) {
        int s0 = csr_src[j + 0 + le];
        int s1 = csr_src[j + 2 + le];
        int s2 = csr_src[j + 4 + le];
        int s3 = csr_src[j + 6 + le];
        float d0 = dinv[s0], d1 = dinv[s1], d2 = dinv[s2], d3 = dinv[s3];
        half8v v0 = *(const half8v*)(hs + (size_t)s0 * 256 + lf * 8);
        half8v v1 = *(const half8v*)(hs + (size_t)s1 * 256 + lf * 8);
        half8v v2 = *(const half8v*)(hs + (size_t)s2 * 256 + lf * 8);
        half8v v3 = *(const half8v*)(hs + (size_t)s3 * 256 + lf * 8);
#pragma unroll
        for (int u = 0; u < 8; ++u)
            acc[u] += (d0 * (float)v0[u] + d1 * (float)v1[u]) +
                      (d2 * (float)v2[u] + d3 * (float)v3[u]);
    }
    for (; j + le < end; j += 2) {
        int s = csr_src[j + le];
        float ds = dinv[s];
        half8v v = *(const half8v*)(hs + (size_t)s * 256 + lf * 8);
#pragma unroll
        for (int u = 0; u < 8; ++u) acc[u] += ds * (float)v[u];
    }
#pragma unroll
    for (int u = 0; u < 8; ++u) acc[u] += __shfl_xor(acc[u], 32, 64);
    float di = dinv[i];
    half8v sv = *(const half8v*)(hs + (size_t)i * 256 + lf * 8);
    float q0 = 0.f, q1 = 0.f;
#pragma unroll
    for (int u = 0; u < 8; ++u) {
        float o = fmaxf((acc[u] + di * (float)sv[u]) * di + b1[lf * 8 + u], 0.f);
        q0 += o * Wft[lf * 8 + u];
        q1 += o * Wft[256 + lf * 8 + u];
    }
#pragma unroll
    for (int off = 16; off > 0; off >>= 1) {
        q0 += __shfl_xor(q0, off, 64);
        q1 += __shfl_xor(q1, off, 64);
    }
    if (l == 0) q[i] = make_float2(q0 * di, q1 * di);
}

// ---------------- gn[i] = (sum_j q[j] + q[i]) * dinv[i] ----------------
__global__ __launch_bounds__(256) void gather_gn(const float2* __restrict__ q,
                                                 const int* __restrict__ rowptr,
                                                 const int* __restrict__ csr_src,
                                                 const float* __restrict__ dinv,
                                                 float2* __restrict__ gn) {
    int i = blockIdx.x * blockDim.x + threadIdx.x;
    if (i >= NN) return;
    int start = rowptr[i], end = rowptr[i + 1];
    float a0 = 0.f, a1 = 0.f;
    for (int j = start; j < end; ++j) {
        float2 v = q[csr_src[j]];
        a0 += v.x;
        a1 += v.y;
    }
    float2 self = q[i];
    float di = dinv[i];
    gn[i] = make_float2((a0 + self.x) * di, (a1 + self.y) * di);
}

// ---------------- final edge kernel ----------------
__global__ __launch_bounds__(256) void edge_out(const float2* __restrict__ gn,
                                                const int* __restrict__ src,
                                                const int* __restrict__ dst,
                                                const int2* __restrict__ ecat,
                                                const float2* __restrict__ ev,
                                                const float* __restrict__ fW1,
                                                const float2* __restrict__ t0,
                                                const float2* __restrict__ t1,
                                                const float* __restrict__ fb1,
                                                const float* __restrict__ fW2,
                                                const float* __restrict__ fb2,
                                                float2* __restrict__ out) {
    int e = blockIdx.x * blockDim.x + threadIdx.x;
    if (e >= EE) return;
    int s = src[e], d = dst[e];
    float2 gs = gn[s], gd = gn[d];
    int2 c = ecat[e];
    float2 v = ev[e];
    float2 e0 = t0[c.x], e1 = t1[c.y];
    float z0 = gs.x - gd.x + v.x * fW1[128 * 2 + 0] + v.y * fW1[129 * 2 + 0] + e0.x + e1.x;
    float z1 = gs.y - gd.y + v.x * fW1[128 * 2 + 1] + v.y * fW1[129 * 2 + 1] + e0.y + e1.y;
    float y0 = fmaxf(z0 + fb1[0], 0.f);
    float y1 = fmaxf(z1 + fb1[1], 0.f);
    out[e] = make_float2(y0 * fW2[0] + y1 * fW2[2] + fb2[0],
                         y0 * fW2[1] + y1 * fW2[3] + fb2[1]);
}

extern "C" void kernel_launch(void* const* d_in, const int* in_sizes, int n_in,
                              void* d_out, int out_size, void* d_ws, size_t ws_size,
                              hipStream_t stream) {
    const float* x    = (const float*)d_in[0];
    const int*   eidx = (const int*)d_in[1];
    const int*   src  = eidx;
    const int*   dst  = eidx + EE;
    const int*   ecat = (const int*)d_in[2];
    const float* ev   = (const float*)d_in[3];
    const float* W1   = (const float*)d_in[4];
    const float* b1   = (const float*)d_in[5];
    const float* W2   = (const float*)d_in[6];
    // b2 (d_in[7]) cancels in gn[s]-gn[d]; unused.
    const float* emb0 = (const float*)d_in[8];
    const float* emb1 = (const float*)d_in[9];
    const float* fW1  = (const float*)d_in[10];
    const float* fb1  = (const float*)d_in[11];
    const float* fW2  = (const float*)d_in[12];
    const float* fb2  = (const float*)d_in[13];
    float* out = (float*)d_out;

    char* ws = (char*)d_ws;
    size_t off = 0;
    auto alloc = [&](size_t bytes) {
        void* p = ws + off;
        off = (off + bytes + 255) & ~(size_t)255;
        return p;
    };
    int*      deg     = (int*)alloc((size_t)NN * 4);
    float*    dinv    = (float*)alloc((size_t)NN * 4);
    int*      rowptr  = (int*)alloc((size_t)(NN + 1) * 4);
    int*      bsum    = (int*)alloc((size_t)NB * 4);
    int*      epos    = (int*)alloc((size_t)EE * 4);
    int*      csr_src = (int*)alloc((size_t)EE * 4);
    _Float16* W1T     = (_Float16*)alloc((size_t)256 * 256 * 2);
    _Float16* h1s     = (_Float16*)alloc((size_t)NN * 256 * 2);    // 25.6 MB fp16
    float2*   q       = (float2*)alloc((size_t)NN * 8);
    float2*   gn      = (float2*)alloc((size_t)NN * 8);
    float*    Wft     = (float*)alloc(512 * 4);
    float2*   t0      = (float2*)alloc(20 * 8);
    float2*   t1      = (float2*)alloc(20 * 8);

    hipMemsetAsync(deg, 0, (size_t)NN * 4, stream);

    // deg/epos atomics + W1 transpose + tiny projections (one dispatch)
    deg_prep<<<DEGB + 17, 256, 0, stream>>>(dst, deg, epos,
                                            W1, W2, fW1, emb0, emb1,
                                            W1T, Wft, t0, t1);

    // scan -> rowptr (+dinv)
    scan_partial<<<NB, 1024, 0, stream>>>(deg, rowptr, bsum);
    scan_add_dinv<<<(NN + 255) / 256, 256, 0, stream>>>(rowptr, bsum, deg, dinv);

    // CSR fill (first) + GEMM (counted-vmcnt dbuf, setprio) in one dispatch
    gemm_fill<<<FILLB + GEMMB, 512, 0, stream>>>(x, W1T, h1s, NN,
                                                 src, dst, rowptr, epos, csr_src);

    // fused gather + relu + project -> q [N,2]  (single dispatch)
    gather_project<<<(NN + 3) / 4, 256, 0, stream>>>(
        h1s, rowptr, csr_src, dinv, b1, Wft, q);
    // gn
    gather_gn<<<(NN + 255) / 256, 256, 0, stream>>>(q, rowptr, csr_src, dinv, gn);
    // edges
    edge_out<<<(EE + 255) / 256, 256, 0, stream>>>(
        gn, src, dst, (const int2*)ecat, (const float2*)ev,
        fW1, t0, t1, fb1, fW2, fb2, (float2*)out);
}